// Round 8
// baseline (71.249 us; speedup 1.0000x reference)
//
#include <hip/hip_runtime.h>
#include <math.h>

#define G 256
#define M 256
#define NNODES (G*M)
#define EDGES (NNODES*16)   // 1,048,576
#define C 3
#define K 5
#define D 128
#define GM (G*M)            // 65536

// Workspace layout (floats):
#define OFF_U0   0
#define OFF_MK0  196608
#define OFF_U1   393216
#define OFF_A0   589824
#define OFF_AK0  655360
#define OFF_A1   720896
#define OFF_MST  786432
#define OFF_AST  787200
// scalar-reduction slots (all RMW-atomic traffic, zeroed each call):
#define OFF_SINFO 787456            // 8 slots
#define OFF_SL2   787464            // 8 slots
#define OFF_SPATH 787472            // 8 slots
#define OFF_CNT   787480            // int counter (+7 pad)
// zero region must be a multiple of 16 BYTES (round-5 lesson: +4B tail knocks
// the runtime fill off the dwordx4 fast path => 40 us instead of ~1 us).
#define ZERO_FLOATS 787488          // 3,149,952 B, 16B-multiple
#define NB_EDGE  512                // edge blocks (256 thr x 8 edges)
#define NB_EMB   384                // emb blocks appended to passA grid

__device__ __forceinline__ float waveReduceSum(float v) {
    #pragma unroll
    for (int o = 32; o > 0; o >>= 1) v += __shfl_xor(v, o, 64);
    return v;
}
__device__ __forceinline__ float waveReduceMax(float v) {
    #pragma unroll
    for (int o = 32; o > 0; o >>= 1) v = fmaxf(v, __shfl_xor(v, o, 64));
    return v;
}

// Node 2: edge blocks scatter row-s / col-t slices of Mdj & Adj and
// atomicAdd info/l2 partials into 8 slots; emb blocks compute H_emb.
__global__ void passA(const float* __restrict__ sij, const int* __restrict__ ei,
                      const int* __restrict__ s, const int* __restrict__ t,
                      const float* __restrict__ hg, const float* __restrict__ Hm,
                      float* __restrict__ out, float* __restrict__ ws) {
    __shared__ int   sS[G], sT[G];
    __shared__ float sc[2][K];
    __shared__ float att[2][K];
    __shared__ float sInfo[4], sL2[4];

    if (blockIdx.x >= NB_EDGE) {
        // ---- H_emb: 2 (c,g) pairs per block, 128 threads each ----
        int half = threadIdx.x >> 7;           // 0 or 1
        int d = threadIdx.x & 127;
        int pair = (blockIdx.x - NB_EDGE) * 2 + half;   // c*G + g
        int c = pair / G, g = pair - c * G;
        float h = hg[g * D + d];
        if (d < K) sc[half][d] = 0.f;
        __syncthreads();
        #pragma unroll
        for (int k = 0; k < K; ++k) {
            float p = h * Hm[(c * K + k) * D + d];
            p = waveReduceSum(p);
            if ((threadIdx.x & 63) == 0) atomicAdd(&sc[half][k], p);
        }
        __syncthreads();
        if (d == 0) {
            float m = sc[half][0];
            #pragma unroll
            for (int k = 1; k < K; ++k) m = fmaxf(m, sc[half][k]);
            float sum = 0.f, ex[K];
            #pragma unroll
            for (int k = 0; k < K; ++k) { ex[k] = __expf(sc[half][k] - m); sum += ex[k]; }
            #pragma unroll
            for (int k = 0; k < K; ++k) att[half][k] = ex[k] / sum;
        }
        __syncthreads();
        float o = 0.f;
        #pragma unroll
        for (int k = 0; k < K; ++k) o += att[half][k] * Hm[(c * K + k) * D + d];
        out[pair * D + d] = o;
        return;
    }

    // ---- edge pass: 8 edges/thread ----
    sS[threadIdx.x] = s[threadIdx.x];
    sT[threadIdx.x] = t[threadIdx.x];
    __syncthreads();

    float* u0  = ws + OFF_U0;
    float* mk0 = ws + OFF_MK0;
    float* a0  = ws + OFF_A0;
    float* ak0 = ws + OFF_AK0;
    float* Mst = ws + OFF_MST;
    float* Ast = ws + OFF_AST;

    int tid = blockIdx.x * 256 + threadIdx.x;   // 0..131071
    int e0 = tid * 8;
    int4 srcA = *(const int4*)(ei + e0);
    int4 srcB = *(const int4*)(ei + e0 + 4);
    int4 dstA = *(const int4*)(ei + EDGES + e0);
    int4 dstB = *(const int4*)(ei + EDGES + e0 + 4);
    float4 v0a = *(const float4*)(sij + 0 * EDGES + e0);
    float4 v0b = *(const float4*)(sij + 0 * EDGES + e0 + 4);
    float4 v1a = *(const float4*)(sij + 1 * EDGES + e0);
    float4 v1b = *(const float4*)(sij + 1 * EDGES + e0 + 4);
    float4 v2a = *(const float4*)(sij + 2 * EDGES + e0);
    float4 v2b = *(const float4*)(sij + 2 * EDGES + e0 + 4);

    int srcp[8], dstp[8];
    float vp[3][8];
    *(int4*)&srcp[0] = srcA;  *(int4*)&srcp[4] = srcB;
    *(int4*)&dstp[0] = dstA;  *(int4*)&dstp[4] = dstB;
    *(float4*)&vp[0][0] = v0a; *(float4*)&vp[0][4] = v0b;
    *(float4*)&vp[1][0] = v1a; *(float4*)&vp[1][4] = v1b;
    *(float4*)&vp[2][0] = v2a; *(float4*)&vp[2][4] = v2b;

    float info = 0.f, l2 = 0.f;
    #pragma unroll
    for (int j = 0; j < 8; ++j) {
        int src = srcp[j], dst = dstp[j];
        int g = src >> 8;
        int r = src & 255;
        int c = dst - (g << 8);
        float v[C] = { vp[0][j], vp[1][j], vp[2][j] };
        if (r == sS[g]) {
            #pragma unroll
            for (int cc = 0; cc < C; ++cc) atomicAdd(&u0[cc * GM + (g << 8) + c], v[cc]);
            atomicAdd(&a0[(g << 8) + c], 1.0f);
            if (c == sT[g]) {
                #pragma unroll
                for (int cc = 0; cc < C; ++cc) atomicAdd(&Mst[cc * G + g], v[cc]);
                atomicAdd(&Ast[g], 1.0f);
            }
        }
        if (c == sT[g]) {
            #pragma unroll
            for (int cc = 0; cc < C; ++cc) atomicAdd(&mk0[cc * GM + (g << 8) + r], v[cc]);
            atomicAdd(&ak0[(g << 8) + r], 1.0f);
        }
        #pragma unroll
        for (int cc = 0; cc < C; ++cc) {
            float x = v[cc];
            info += x * __logf(x * 2.0f + 1e-6f)
                  + (1.0f - x) * __logf((1.0f - x) / 0.500001f + 1e-6f);
            l2 += x * x;
        }
    }
    info = waveReduceSum(info);
    l2 = waveReduceSum(l2);
    int wid = threadIdx.x >> 6, lane = threadIdx.x & 63;
    if (lane == 0) { sInfo[wid] = info; sL2[wid] = l2; }
    __syncthreads();
    if (threadIdx.x == 0) {
        float i2 = 0.f, l = 0.f;
        #pragma unroll
        for (int w = 0; w < 4; ++w) { i2 += sInfo[w]; l += sL2[w]; }
        // 8-slot atomic partials (64 blocks/slot); visible to later kernels
        // via the dispatch-boundary release — no fence needed.
        atomicAdd(ws + OFF_SINFO + (blockIdx.x & 7), i2);
        atomicAdd(ws + OFF_SL2   + (blockIdx.x & 7), l);
    }
}

// Node 3: u1 = u0 @ Mdj (per class), a1 = a0 @ Adj, edge-wise, 8 edges/thread.
__global__ void passB(const float* __restrict__ sij, const int* __restrict__ ei,
                      float* __restrict__ ws) {
    const float* u0 = ws + OFF_U0;
    const float* a0 = ws + OFF_A0;
    float* u1 = ws + OFF_U1;
    float* a1 = ws + OFF_A1;

    int tid = blockIdx.x * 256 + threadIdx.x;
    int e0 = tid * 8;
    int4 srcA = *(const int4*)(ei + e0);
    int4 srcB = *(const int4*)(ei + e0 + 4);
    int4 dstA = *(const int4*)(ei + EDGES + e0);
    int4 dstB = *(const int4*)(ei + EDGES + e0 + 4);
    int srcp[8], dstp[8];
    *(int4*)&srcp[0] = srcA;  *(int4*)&srcp[4] = srcB;
    *(int4*)&dstp[0] = dstA;  *(int4*)&dstp[4] = dstB;

    int gi[8];
    float ar[8];
    #pragma unroll
    for (int j = 0; j < 8; ++j) {
        gi[j] = (srcp[j] >> 8 << 8);             // g*256
        ar[j] = a0[gi[j] + (srcp[j] & 255)];     // 8 independent gathers in flight
    }
    #pragma unroll
    for (int j = 0; j < 8; ++j) {
        if (ar[j] == 0.0f) continue;   // u0[g][r]==0 too (sij>0)
        int r = srcp[j] & 255;
        int c = dstp[j] - gi[j];
        atomicAdd(&a1[gi[j] + c], ar[j]);
        int e = e0 + j;
        #pragma unroll
        for (int cc = 0; cc < C; ++cc) {
            float ur = u0[cc * GM + gi[j] + r];
            atomicAdd(&u1[cc * GM + gi[j] + c], ur * sij[cc * EDGES + e]);
        }
    }
}

// Node 4: path loss per (c,g) + fused scalar finalize.
// Fence-FREE last-block-done: all cross-block data moves via RMW atomics
// (performed at the device coherence point), ordering via a data dependency
// on the returned old value — no L2-writeback threadfence (round-7 lesson:
// 768 device fences cost ~17 us).
__global__ void pathFinal(const float* __restrict__ pw, float* __restrict__ ws,
                          float* __restrict__ out) {
    int b = blockIdx.x;          // c*G + g
    int c = b / G, g = b - c * G;
    int x = threadIdx.x;         // 256 threads
    const float* u0  = ws + OFF_U0;
    const float* mk0 = ws + OFF_MK0;
    const float* u1  = ws + OFF_U1;
    const float* a0  = ws + OFF_A0;
    const float* ak0 = ws + OFF_AK0;
    const float* a1  = ws + OFF_A1;
    __shared__ float s0[4], s1[4];
    __shared__ float slotv[24];
    __shared__ int isLast;

    int gi  = (g << 8) + x;
    int cgi = c * GM + gi;
    float ak = ak0[gi], mk = mk0[cgi];
    float den0 = a0[gi] * ak;  den0 = (den0 == 0.f) ? 1e-8f : den0;
    float t0 = u0[cgi] * mk / den0;
    float den1 = a1[gi] * ak;  den1 = (den1 == 0.f) ? 1e-8f : den1;
    float t1 = u1[cgi] * mk / den1;

    t0 = waveReduceMax(t0);
    t1 = waveReduceMax(t1);
    int wid = x >> 6, lane = x & 63;
    if (lane == 0) { s0[wid] = t0; s1[wid] = t1; }
    __syncthreads();
    if (x == 0) {
        float m0 = s0[0], m1 = s1[0];
        #pragma unroll
        for (int w = 1; w < 4; ++w) { m0 = fmaxf(m0, s0[w]); m1 = fmaxf(m1, s1[w]); }
        float w1 = fminf(fmaxf(pw[1], 1e-10f), 1.0f);
        float w2 = fminf(fmaxf(pw[2], 1e-10f), 1.0f);
        float A = ws[OFF_AST + g];  A = (A == 0.f) ? 1e-8f : A;
        float uk = ws[OFF_MST + c * G + g] / A;   // l+1=1 -> identity power
        uk += w1 * (m0 + 1e-8f);
        uk += w2 * sqrtf(m1 + 1e-8f);             // exponent 1/2 -> sqrt
        uk *= (1.0f / 3.0f);                      // / MAXLEN
        // publish via RMW (coherence-point), then signal; the asm launder
        // forces the slot-add's completion (vmcnt drain on `old`) and blocks
        // compile-time reordering of the counter past it.
        float old = atomicAdd(ws + OFF_SPATH + (b & 7), __logf(uk + 1e-8f));
        asm volatile("" : "+v"(old) :: "memory");
        int done = atomicAdd((int*)(ws + OFF_CNT), 1);
        isLast = (done == C * G - 1);
    }
    __syncthreads();
    if (!isLast) return;

    // ---- last block: RMW-read the 24 slots, write the 3 scalars ----
    if (x < 24) slotv[x] = atomicAdd(ws + OFF_SINFO + x, 0.0f);
    __syncthreads();
    if (x == 0) {
        float info = 0.f, l2 = 0.f, path = 0.f;
        #pragma unroll
        for (int w = 0; w < 8; ++w) {
            info += slotv[w];
            l2   += slotv[8 + w];
            path += slotv[16 + w];
        }
        out[C * G * D + 0] = info / (float)(C * EDGES);            // L_info mean
        out[C * G * D + 1] = -path / (float)(C * G);               // L_path mean
        out[C * G * D + 2] = l2 / (2.0f * (float)G * (float)C);    // L_l2 mean
    }
}

extern "C" void kernel_launch(void* const* d_in, const int* in_sizes, int n_in,
                              void* d_out, int out_size, void* d_ws, size_t ws_size,
                              hipStream_t stream) {
    const float* hg  = (const float*)d_in[0];
    const float* Hm  = (const float*)d_in[1];
    const float* pw  = (const float*)d_in[2];
    const float* sij = (const float*)d_in[3];
    const int*   ei  = (const int*)d_in[4];
    // d_in[5] = batch (unused: batch[src] == src >> 8)
    const int*   s   = (const int*)d_in[6];
    const int*   t   = (const int*)d_in[7];
    float* out = (float*)d_out;
    float* ws  = (float*)d_ws;

    // 3,149,952 bytes — 16B multiple keeps the runtime fill on the fast path.
    hipMemsetAsync(d_ws, 0, ZERO_FLOATS * sizeof(float), stream);
    passA<<<NB_EDGE + NB_EMB, 256, 0, stream>>>(sij, ei, s, t, hg, Hm, out, ws);
    passB<<<NB_EDGE, 256, 0, stream>>>(sij, ei, ws);
    pathFinal<<<C * G, M, 0, stream>>>(pw, ws, out);
}

// Round 9
// 44.970 us; speedup vs baseline: 1.5844x; 1.5844x over previous
//
#include <hip/hip_runtime.h>
#include <math.h>

#define G 256
#define M 256
#define NNODES (G*M)
#define EDGES (NNODES*16)   // 1,048,576
#define C 3
#define K 5
#define D 128
#define GM (G*M)            // 65536

// Workspace layout (floats):
#define OFF_U0   0
#define OFF_MK0  196608
#define OFF_U1   393216
#define OFF_A0   589824
#define OFF_AK0  655360
#define OFF_A1   720896
#define OFF_MST  786432
#define OFF_AST  787200
// ---- contention-aware scalar plumbing (round-8 lesson: ~13ns per serialized
// SAME-LINE atomic; every slot/counter below sits on its own 128-B L2 line) ----
#define OFF_SLOTS 787456            // 8 path slots, stride 32 floats (128 B)
#define OFF_CNT8  787712            // 8 int counters, stride 32
#define OFF_SUPER 787968            // 1 int super-counter (own line, 32 pad)
// zero region must be a multiple of 16 BYTES (round-5 lesson: +4B tail knocks
// the runtime fill off the dwordx4 fast path => 40 us instead of ~1 us).
#define ZERO_FLOATS 788000          // 3,152,000 B, 16B-multiple
// per-block partials (written unconditionally each call, no zeroing needed;
// cross a kernel boundary before being read -> plain stores are safe)
#define NB_EDGE  512                // edge blocks (256 thr x 8 edges)
#define NB_EMB   384                // emb blocks appended to passA grid
#define OFF_PINFO 788000
#define OFF_PL2   (OFF_PINFO + NB_EDGE)

__device__ __forceinline__ float waveReduceSum(float v) {
    #pragma unroll
    for (int o = 32; o > 0; o >>= 1) v += __shfl_xor(v, o, 64);
    return v;
}
__device__ __forceinline__ float waveReduceMax(float v) {
    #pragma unroll
    for (int o = 32; o > 0; o >>= 1) v = fmaxf(v, __shfl_xor(v, o, 64));
    return v;
}

// Node 2: edge blocks scatter row-s / col-t slices of Mdj & Adj + info/l2
// per-block partials (plain stores); emb blocks compute H_emb.
__global__ void passA(const float* __restrict__ sij, const int* __restrict__ ei,
                      const int* __restrict__ s, const int* __restrict__ t,
                      const float* __restrict__ hg, const float* __restrict__ Hm,
                      float* __restrict__ out, float* __restrict__ ws) {
    __shared__ int   sS[G], sT[G];
    __shared__ float sc[2][K];
    __shared__ float att[2][K];
    __shared__ float sInfo[4], sL2[4];

    if (blockIdx.x >= NB_EDGE) {
        // ---- H_emb: 2 (c,g) pairs per block, 128 threads each ----
        int half = threadIdx.x >> 7;           // 0 or 1
        int d = threadIdx.x & 127;
        int pair = (blockIdx.x - NB_EDGE) * 2 + half;   // c*G + g
        int c = pair / G, g = pair - c * G;
        float h = hg[g * D + d];
        if (d < K) sc[half][d] = 0.f;
        __syncthreads();
        #pragma unroll
        for (int k = 0; k < K; ++k) {
            float p = h * Hm[(c * K + k) * D + d];
            p = waveReduceSum(p);
            if ((threadIdx.x & 63) == 0) atomicAdd(&sc[half][k], p);
        }
        __syncthreads();
        if (d == 0) {
            float m = sc[half][0];
            #pragma unroll
            for (int k = 1; k < K; ++k) m = fmaxf(m, sc[half][k]);
            float sum = 0.f, ex[K];
            #pragma unroll
            for (int k = 0; k < K; ++k) { ex[k] = __expf(sc[half][k] - m); sum += ex[k]; }
            #pragma unroll
            for (int k = 0; k < K; ++k) att[half][k] = ex[k] / sum;
        }
        __syncthreads();
        float o = 0.f;
        #pragma unroll
        for (int k = 0; k < K; ++k) o += att[half][k] * Hm[(c * K + k) * D + d];
        out[pair * D + d] = o;
        return;
    }

    // ---- edge pass: 8 edges/thread ----
    sS[threadIdx.x] = s[threadIdx.x];
    sT[threadIdx.x] = t[threadIdx.x];
    __syncthreads();

    float* u0  = ws + OFF_U0;
    float* mk0 = ws + OFF_MK0;
    float* a0  = ws + OFF_A0;
    float* ak0 = ws + OFF_AK0;
    float* Mst = ws + OFF_MST;
    float* Ast = ws + OFF_AST;

    int tid = blockIdx.x * 256 + threadIdx.x;   // 0..131071
    int e0 = tid * 8;
    int4 srcA = *(const int4*)(ei + e0);
    int4 srcB = *(const int4*)(ei + e0 + 4);
    int4 dstA = *(const int4*)(ei + EDGES + e0);
    int4 dstB = *(const int4*)(ei + EDGES + e0 + 4);
    float4 v0a = *(const float4*)(sij + 0 * EDGES + e0);
    float4 v0b = *(const float4*)(sij + 0 * EDGES + e0 + 4);
    float4 v1a = *(const float4*)(sij + 1 * EDGES + e0);
    float4 v1b = *(const float4*)(sij + 1 * EDGES + e0 + 4);
    float4 v2a = *(const float4*)(sij + 2 * EDGES + e0);
    float4 v2b = *(const float4*)(sij + 2 * EDGES + e0 + 4);

    int srcp[8], dstp[8];
    float vp[3][8];
    *(int4*)&srcp[0] = srcA;  *(int4*)&srcp[4] = srcB;
    *(int4*)&dstp[0] = dstA;  *(int4*)&dstp[4] = dstB;
    *(float4*)&vp[0][0] = v0a; *(float4*)&vp[0][4] = v0b;
    *(float4*)&vp[1][0] = v1a; *(float4*)&vp[1][4] = v1b;
    *(float4*)&vp[2][0] = v2a; *(float4*)&vp[2][4] = v2b;

    float info = 0.f, l2 = 0.f;
    #pragma unroll
    for (int j = 0; j < 8; ++j) {
        int src = srcp[j], dst = dstp[j];
        int g = src >> 8;
        int r = src & 255;
        int c = dst - (g << 8);
        float v[C] = { vp[0][j], vp[1][j], vp[2][j] };
        if (r == sS[g]) {
            #pragma unroll
            for (int cc = 0; cc < C; ++cc) atomicAdd(&u0[cc * GM + (g << 8) + c], v[cc]);
            atomicAdd(&a0[(g << 8) + c], 1.0f);
            if (c == sT[g]) {
                #pragma unroll
                for (int cc = 0; cc < C; ++cc) atomicAdd(&Mst[cc * G + g], v[cc]);
                atomicAdd(&Ast[g], 1.0f);
            }
        }
        if (c == sT[g]) {
            #pragma unroll
            for (int cc = 0; cc < C; ++cc) atomicAdd(&mk0[cc * GM + (g << 8) + r], v[cc]);
            atomicAdd(&ak0[(g << 8) + r], 1.0f);
        }
        #pragma unroll
        for (int cc = 0; cc < C; ++cc) {
            float x = v[cc];
            info += x * __logf(x * 2.0f + 1e-6f)
                  + (1.0f - x) * __logf((1.0f - x) / 0.500001f + 1e-6f);
            l2 += x * x;
        }
    }
    info = waveReduceSum(info);
    l2 = waveReduceSum(l2);
    int wid = threadIdx.x >> 6, lane = threadIdx.x & 63;
    if (lane == 0) { sInfo[wid] = info; sL2[wid] = l2; }
    __syncthreads();
    if (threadIdx.x == 0) {
        float i2 = 0.f, l = 0.f;
        #pragma unroll
        for (int w = 0; w < 4; ++w) { i2 += sInfo[w]; l += sL2[w]; }
        ws[OFF_PINFO + blockIdx.x] = i2;   // plain stores; read after a kernel
        ws[OFF_PL2 + blockIdx.x] = l;      // boundary -> visible device-wide
    }
}

// Node 3: u1 = u0 @ Mdj (per class), a1 = a0 @ Adj, edge-wise, 8 edges/thread.
__global__ void passB(const float* __restrict__ sij, const int* __restrict__ ei,
                      float* __restrict__ ws) {
    const float* u0 = ws + OFF_U0;
    const float* a0 = ws + OFF_A0;
    float* u1 = ws + OFF_U1;
    float* a1 = ws + OFF_A1;

    int tid = blockIdx.x * 256 + threadIdx.x;
    int e0 = tid * 8;
    int4 srcA = *(const int4*)(ei + e0);
    int4 srcB = *(const int4*)(ei + e0 + 4);
    int4 dstA = *(const int4*)(ei + EDGES + e0);
    int4 dstB = *(const int4*)(ei + EDGES + e0 + 4);
    int srcp[8], dstp[8];
    *(int4*)&srcp[0] = srcA;  *(int4*)&srcp[4] = srcB;
    *(int4*)&dstp[0] = dstA;  *(int4*)&dstp[4] = dstB;

    int gi[8];
    float ar[8];
    #pragma unroll
    for (int j = 0; j < 8; ++j) {
        gi[j] = (srcp[j] >> 8 << 8);             // g*256
        ar[j] = a0[gi[j] + (srcp[j] & 255)];     // 8 independent gathers in flight
    }
    #pragma unroll
    for (int j = 0; j < 8; ++j) {
        if (ar[j] == 0.0f) continue;   // u0[g][r]==0 too (sij>0)
        int r = srcp[j] & 255;
        int c = dstp[j] - gi[j];
        atomicAdd(&a1[gi[j] + c], ar[j]);
        int e = e0 + j;
        #pragma unroll
        for (int cc = 0; cc < C; ++cc) {
            float ur = u0[cc * GM + gi[j] + r];
            atomicAdd(&u1[cc * GM + gi[j] + c], ur * sij[cc * EDGES + e]);
        }
    }
}

// Node 4: path loss per (c,g) + fused scalar finalize.
// Contention-aware last-block-done: path values go into 8 slots on 8 distinct
// L2 lines (96 serialized RMWs per line, ~1.2us, chains parallel); completion
// tracked by an 8-counter tree (own lines) -> 1 super-counter. Ordering via
// data dependency on the atomic's returned value (vmcnt drain), no fences.
__global__ void pathFinal(const float* __restrict__ pw, float* __restrict__ ws,
                          float* __restrict__ out) {
    int b = blockIdx.x;          // c*G + g
    int c = b / G, g = b - c * G;
    int x = threadIdx.x;         // 256 threads
    const float* u0  = ws + OFF_U0;
    const float* mk0 = ws + OFF_MK0;
    const float* u1  = ws + OFF_U1;
    const float* a0  = ws + OFF_A0;
    const float* ak0 = ws + OFF_AK0;
    const float* a1  = ws + OFF_A1;
    __shared__ float s0[4], s1[4], s2[4];
    __shared__ float slotv[8];
    __shared__ int isLast;

    int gi  = (g << 8) + x;
    int cgi = c * GM + gi;
    float ak = ak0[gi], mk = mk0[cgi];
    float den0 = a0[gi] * ak;  den0 = (den0 == 0.f) ? 1e-8f : den0;
    float t0 = u0[cgi] * mk / den0;
    float den1 = a1[gi] * ak;  den1 = (den1 == 0.f) ? 1e-8f : den1;
    float t1 = u1[cgi] * mk / den1;

    t0 = waveReduceMax(t0);
    t1 = waveReduceMax(t1);
    int wid = x >> 6, lane = x & 63;
    if (lane == 0) { s0[wid] = t0; s1[wid] = t1; }
    __syncthreads();
    if (x == 0) {
        isLast = 0;
        float m0 = s0[0], m1 = s1[0];
        #pragma unroll
        for (int w = 1; w < 4; ++w) { m0 = fmaxf(m0, s0[w]); m1 = fmaxf(m1, s1[w]); }
        float w1 = fminf(fmaxf(pw[1], 1e-10f), 1.0f);
        float w2 = fminf(fmaxf(pw[2], 1e-10f), 1.0f);
        float A = ws[OFF_AST + g];  A = (A == 0.f) ? 1e-8f : A;
        float uk = ws[OFF_MST + c * G + g] / A;   // l+1=1 -> identity power
        uk += w1 * (m0 + 1e-8f);
        uk += w2 * sqrtf(m1 + 1e-8f);             // exponent 1/2 -> sqrt
        uk *= (1.0f / 3.0f);                      // / MAXLEN
        int slot = b & 7;
        // 1) publish path value into this slot's line (RMW, coherence point)
        float old = atomicAdd(ws + OFF_SLOTS + slot * 32, __logf(uk + 1e-8f));
        asm volatile("" : "+v"(old) :: "memory");   // complete before counting
        // 2) per-slot counter (own line); 96 blocks per slot
        int done = atomicAdd((int*)(ws + OFF_CNT8) + slot * 32, 1);
        if (done == 96 - 1) {
            asm volatile("" : "+v"(done) :: "memory");
            // 3) slot-last blocks race on the super-counter (8 adds total)
            int sdone = atomicAdd((int*)(ws + OFF_SUPER), 1);
            isLast = (sdone == 8 - 1);
        }
    }
    __syncthreads();
    if (!isLast) return;

    // ---- global-last block: reduce partials -> 3 scalar outputs ----
    // PINFO/PL2 were plain-stored by passA (kernel boundary passed -> visible);
    // path slots are same-dispatch -> RMW-read them.
    if (x < 8) slotv[x] = atomicAdd(ws + OFF_SLOTS + x * 32, 0.0f);
    float info = 0.f, l2 = 0.f;
    for (int i = x; i < NB_EDGE; i += 256) {
        info += ws[OFF_PINFO + i];
        l2   += ws[OFF_PL2 + i];
    }
    info = waveReduceSum(info);
    l2   = waveReduceSum(l2);
    if (lane == 0) { s0[wid] = info; s1[wid] = l2; }
    __syncthreads();
    if (x == 0) {
        float i2 = 0.f, l = 0.f, p = 0.f;
        #pragma unroll
        for (int w = 0; w < 4; ++w) { i2 += s0[w]; l += s1[w]; }
        #pragma unroll
        for (int w = 0; w < 8; ++w) p += slotv[w];
        out[C * G * D + 0] = i2 / (float)(C * EDGES);            // L_info mean
        out[C * G * D + 1] = -p / (float)(C * G);                // L_path mean
        out[C * G * D + 2] = l / (2.0f * (float)G * (float)C);   // L_l2 mean
    }
}

extern "C" void kernel_launch(void* const* d_in, const int* in_sizes, int n_in,
                              void* d_out, int out_size, void* d_ws, size_t ws_size,
                              hipStream_t stream) {
    const float* hg  = (const float*)d_in[0];
    const float* Hm  = (const float*)d_in[1];
    const float* pw  = (const float*)d_in[2];
    const float* sij = (const float*)d_in[3];
    const int*   ei  = (const int*)d_in[4];
    // d_in[5] = batch (unused: batch[src] == src >> 8)
    const int*   s   = (const int*)d_in[6];
    const int*   t   = (const int*)d_in[7];
    float* out = (float*)d_out;
    float* ws  = (float*)d_ws;

    // 3,152,000 bytes — 16B multiple keeps the runtime fill on the fast path.
    hipMemsetAsync(d_ws, 0, ZERO_FLOATS * sizeof(float), stream);
    passA<<<NB_EDGE + NB_EMB, 256, 0, stream>>>(sij, ei, s, t, hg, Hm, out, ws);
    passB<<<NB_EDGE, 256, 0, stream>>>(sij, ei, ws);
    pathFinal<<<C * G, M, 0, stream>>>(pw, ws, out);
}

// Round 10
// 44.474 us; speedup vs baseline: 1.6020x; 1.0112x over previous
//
#include <hip/hip_runtime.h>
#include <math.h>

#define G 256
#define M 256
#define NNODES (G*M)
#define EDGES (NNODES*16)   // 1,048,576
#define C 3
#define K 5
#define D 128
#define GM (G*M)            // 65536

// Workspace layout (floats):
#define OFF_U0   0
#define OFF_MK0  196608
#define OFF_U1   393216
#define OFF_A0   589824
#define OFF_AK0  655360
#define OFF_A1   720896
#define OFF_MST  786432
#define OFF_AST  787200
// Zero region: 3,149,824 B = 769 x 4096. Fill fast path needs >=256B
// granularity (R5/R7/R9 lesson: 16B-multiple-but-not-256 => 75 GB/s fill).
#define ZERO_FLOATS 787456
// per-block partials (written unconditionally each call, no zeroing needed)
#define NB_EDGE  512                // edge blocks (256 thr x 8 edges)
#define NB_EMB   384                // emb blocks appended to passA grid
#define OFF_PINFO 787456
#define OFF_PL2   (OFF_PINFO + NB_EDGE)
#define OFF_PPATH (OFF_PL2 + NB_EDGE)  // C*G = 768
#define WS_FLOATS (OFF_PPATH + C*G)

__device__ __forceinline__ float waveReduceSum(float v) {
    #pragma unroll
    for (int o = 32; o > 0; o >>= 1) v += __shfl_xor(v, o, 64);
    return v;
}
__device__ __forceinline__ float waveReduceMax(float v) {
    #pragma unroll
    for (int o = 32; o > 0; o >>= 1) v = fmaxf(v, __shfl_xor(v, o, 64));
    return v;
}

// Pass A (blocks 0..NB_EDGE-1): scatter row-s / col-t slices of Mdj & Adj,
// fused L_info/L_l2 partial sums. 8 edges/thread, vectorized loads, s/t in LDS.
// Blocks NB_EDGE.. : H_emb (independent work, hidden under passA).
__global__ void passA(const float* __restrict__ sij, const int* __restrict__ ei,
                      const int* __restrict__ s, const int* __restrict__ t,
                      const float* __restrict__ hg, const float* __restrict__ Hm,
                      float* __restrict__ out, float* __restrict__ ws) {
    __shared__ int   sS[G], sT[G];
    __shared__ float sc[2][K];
    __shared__ float att[2][K];
    __shared__ float sInfo[4], sL2[4];

    if (blockIdx.x >= NB_EDGE) {
        // ---- H_emb: 2 (c,g) pairs per block, 128 threads each ----
        int half = threadIdx.x >> 7;           // 0 or 1
        int d = threadIdx.x & 127;
        int pair = (blockIdx.x - NB_EDGE) * 2 + half;   // c*G + g
        int c = pair / G, g = pair - c * G;
        float h = hg[g * D + d];
        if (d < K) sc[half][d] = 0.f;
        __syncthreads();
        #pragma unroll
        for (int k = 0; k < K; ++k) {
            float p = h * Hm[(c * K + k) * D + d];
            p = waveReduceSum(p);
            if ((threadIdx.x & 63) == 0) atomicAdd(&sc[half][k], p);
        }
        __syncthreads();
        if (d == 0) {
            float m = sc[half][0];
            #pragma unroll
            for (int k = 1; k < K; ++k) m = fmaxf(m, sc[half][k]);
            float sum = 0.f, ex[K];
            #pragma unroll
            for (int k = 0; k < K; ++k) { ex[k] = __expf(sc[half][k] - m); sum += ex[k]; }
            #pragma unroll
            for (int k = 0; k < K; ++k) att[half][k] = ex[k] / sum;
        }
        __syncthreads();
        float o = 0.f;
        #pragma unroll
        for (int k = 0; k < K; ++k) o += att[half][k] * Hm[(c * K + k) * D + d];
        out[pair * D + d] = o;
        return;
    }

    // ---- edge pass ----
    sS[threadIdx.x] = s[threadIdx.x];
    sT[threadIdx.x] = t[threadIdx.x];
    __syncthreads();

    float* u0  = ws + OFF_U0;
    float* mk0 = ws + OFF_MK0;
    float* a0  = ws + OFF_A0;
    float* ak0 = ws + OFF_AK0;
    float* Mst = ws + OFF_MST;
    float* Ast = ws + OFF_AST;

    int tid = blockIdx.x * 256 + threadIdx.x;   // 0..131071
    int e0 = tid * 8;
    int4 srcA = *(const int4*)(ei + e0);
    int4 srcB = *(const int4*)(ei + e0 + 4);
    int4 dstA = *(const int4*)(ei + EDGES + e0);
    int4 dstB = *(const int4*)(ei + EDGES + e0 + 4);
    float4 v0a = *(const float4*)(sij + 0 * EDGES + e0);
    float4 v0b = *(const float4*)(sij + 0 * EDGES + e0 + 4);
    float4 v1a = *(const float4*)(sij + 1 * EDGES + e0);
    float4 v1b = *(const float4*)(sij + 1 * EDGES + e0 + 4);
    float4 v2a = *(const float4*)(sij + 2 * EDGES + e0);
    float4 v2b = *(const float4*)(sij + 2 * EDGES + e0 + 4);

    int srcp[8], dstp[8];
    float vp[3][8];
    *(int4*)&srcp[0] = srcA;  *(int4*)&srcp[4] = srcB;
    *(int4*)&dstp[0] = dstA;  *(int4*)&dstp[4] = dstB;
    *(float4*)&vp[0][0] = v0a; *(float4*)&vp[0][4] = v0b;
    *(float4*)&vp[1][0] = v1a; *(float4*)&vp[1][4] = v1b;
    *(float4*)&vp[2][0] = v2a; *(float4*)&vp[2][4] = v2b;

    float info = 0.f, l2 = 0.f;
    #pragma unroll
    for (int j = 0; j < 8; ++j) {
        int src = srcp[j], dst = dstp[j];
        int g = src >> 8;
        int r = src & 255;
        int c = dst - (g << 8);
        float v[C] = { vp[0][j], vp[1][j], vp[2][j] };
        if (r == sS[g]) {
            #pragma unroll
            for (int cc = 0; cc < C; ++cc) atomicAdd(&u0[cc * GM + (g << 8) + c], v[cc]);
            atomicAdd(&a0[(g << 8) + c], 1.0f);
            if (c == sT[g]) {
                #pragma unroll
                for (int cc = 0; cc < C; ++cc) atomicAdd(&Mst[cc * G + g], v[cc]);
                atomicAdd(&Ast[g], 1.0f);
            }
        }
        if (c == sT[g]) {
            #pragma unroll
            for (int cc = 0; cc < C; ++cc) atomicAdd(&mk0[cc * GM + (g << 8) + r], v[cc]);
            atomicAdd(&ak0[(g << 8) + r], 1.0f);
        }
        #pragma unroll
        for (int cc = 0; cc < C; ++cc) {
            float x = v[cc];
            info += x * __logf(x * 2.0f + 1e-6f)
                  + (1.0f - x) * __logf((1.0f - x) / 0.500001f + 1e-6f);
            l2 += x * x;
        }
    }
    info = waveReduceSum(info);
    l2 = waveReduceSum(l2);
    int wid = threadIdx.x >> 6, lane = threadIdx.x & 63;
    if (lane == 0) { sInfo[wid] = info; sL2[wid] = l2; }
    __syncthreads();
    if (threadIdx.x == 0) {
        float i2 = 0.f, l = 0.f;
        #pragma unroll
        for (int w = 0; w < 4; ++w) { i2 += sInfo[w]; l += sL2[w]; }
        ws[OFF_PINFO + blockIdx.x] = i2;
        ws[OFF_PL2 + blockIdx.x] = l;
    }
}

// Pass B: u1 = u0 @ Mdj (per class), a1 = a0 @ Adj, edge-wise, 8 edges/thread.
__global__ void passB(const float* __restrict__ sij, const int* __restrict__ ei,
                      float* __restrict__ ws) {
    const float* u0 = ws + OFF_U0;
    const float* a0 = ws + OFF_A0;
    float* u1 = ws + OFF_U1;
    float* a1 = ws + OFF_A1;

    int tid = blockIdx.x * 256 + threadIdx.x;
    int e0 = tid * 8;
    int4 srcA = *(const int4*)(ei + e0);
    int4 srcB = *(const int4*)(ei + e0 + 4);
    int4 dstA = *(const int4*)(ei + EDGES + e0);
    int4 dstB = *(const int4*)(ei + EDGES + e0 + 4);
    int srcp[8], dstp[8];
    *(int4*)&srcp[0] = srcA;  *(int4*)&srcp[4] = srcB;
    *(int4*)&dstp[0] = dstA;  *(int4*)&dstp[4] = dstB;

    int gi[8];
    float ar[8];
    #pragma unroll
    for (int j = 0; j < 8; ++j) {
        gi[j] = (srcp[j] >> 8 << 8);             // g*256
        ar[j] = a0[gi[j] + (srcp[j] & 255)];     // 8 independent gathers in flight
    }
    #pragma unroll
    for (int j = 0; j < 8; ++j) {
        if (ar[j] == 0.0f) continue;   // u0[g][r]==0 too (sij>0)
        int r = srcp[j] & 255;
        int c = dstp[j] - gi[j];
        atomicAdd(&a1[gi[j] + c], ar[j]);
        int e = e0 + j;
        #pragma unroll
        for (int cc = 0; cc < C; ++cc) {
            float ur = u0[cc * GM + gi[j] + r];
            atomicAdd(&u1[cc * GM + gi[j] + c], ur * sij[cc * EDGES + e]);
        }
    }
}

// Path loss finalize: per (c,g) block max over M -> per-block log stored.
__global__ void pathK(const float* __restrict__ pw, float* __restrict__ ws) {
    int b = blockIdx.x;          // c*G + g
    int c = b / G, g = b - c * G;
    int x = threadIdx.x;         // 256 threads
    const float* u0  = ws + OFF_U0;
    const float* mk0 = ws + OFF_MK0;
    const float* u1  = ws + OFF_U1;
    const float* a0  = ws + OFF_A0;
    const float* ak0 = ws + OFF_AK0;
    const float* a1  = ws + OFF_A1;

    int gi  = (g << 8) + x;
    int cgi = c * GM + gi;
    float ak = ak0[gi], mk = mk0[cgi];
    float den0 = a0[gi] * ak;  den0 = (den0 == 0.f) ? 1e-8f : den0;
    float t0 = u0[cgi] * mk / den0;
    float den1 = a1[gi] * ak;  den1 = (den1 == 0.f) ? 1e-8f : den1;
    float t1 = u1[cgi] * mk / den1;

    t0 = waveReduceMax(t0);
    t1 = waveReduceMax(t1);
    __shared__ float s0[4], s1[4];
    int wid = x >> 6, lane = x & 63;
    if (lane == 0) { s0[wid] = t0; s1[wid] = t1; }
    __syncthreads();
    if (x == 0) {
        float m0 = s0[0], m1 = s1[0];
        #pragma unroll
        for (int w = 1; w < 4; ++w) { m0 = fmaxf(m0, s0[w]); m1 = fmaxf(m1, s1[w]); }
        float w1 = fminf(fmaxf(pw[1], 1e-10f), 1.0f);
        float w2 = fminf(fmaxf(pw[2], 1e-10f), 1.0f);
        float A = ws[OFF_AST + g];  A = (A == 0.f) ? 1e-8f : A;
        float uk = ws[OFF_MST + c * G + g] / A;   // l+1=1 -> identity power
        uk += w1 * (m0 + 1e-8f);
        uk += w2 * sqrtf(m1 + 1e-8f);             // exponent 1/2 -> sqrt
        uk *= (1.0f / 3.0f);                      // / MAXLEN
        ws[OFF_PPATH + b] = __logf(uk + 1e-8f);
    }
}

// Final reduce of all per-block partials -> 3 scalar outputs. One block.
__global__ void finalK(const float* __restrict__ ws, float* __restrict__ out) {
    int tid = threadIdx.x;       // 256 threads
    float info = 0.f, l2 = 0.f, path = 0.f;
    for (int i = tid; i < NB_EDGE; i += 256) {
        info += ws[OFF_PINFO + i];
        l2   += ws[OFF_PL2 + i];
    }
    for (int i = tid; i < C * G; i += 256) path += ws[OFF_PPATH + i];
    info = waveReduceSum(info);
    l2   = waveReduceSum(l2);
    path = waveReduceSum(path);
    __shared__ float sI[4], sL[4], sP[4];
    int wid = tid >> 6, lane = tid & 63;
    if (lane == 0) { sI[wid] = info; sL[wid] = l2; sP[wid] = path; }
    __syncthreads();
    if (tid == 0) {
        float i2 = 0.f, l = 0.f, p = 0.f;
        #pragma unroll
        for (int w = 0; w < 4; ++w) { i2 += sI[w]; l += sL[w]; p += sP[w]; }
        out[C * G * D + 0] = i2 / (float)(C * EDGES);            // L_info mean
        out[C * G * D + 1] = -p / (float)(C * G);                // L_path mean
        out[C * G * D + 2] = l / (2.0f * (float)G * (float)C);   // L_l2 mean
    }
}

extern "C" void kernel_launch(void* const* d_in, const int* in_sizes, int n_in,
                              void* d_out, int out_size, void* d_ws, size_t ws_size,
                              hipStream_t stream) {
    const float* hg  = (const float*)d_in[0];
    const float* Hm  = (const float*)d_in[1];
    const float* pw  = (const float*)d_in[2];
    const float* sij = (const float*)d_in[3];
    const int*   ei  = (const int*)d_in[4];
    // d_in[5] = batch (unused: batch[src] == src >> 8)
    const int*   s   = (const int*)d_in[6];
    const int*   t   = (const int*)d_in[7];
    float* out = (float*)d_out;
    float* ws  = (float*)d_ws;

    // 3,149,824 bytes = 769 x 4096 — keeps the runtime fill on the fast path.
    hipMemsetAsync(d_ws, 0, ZERO_FLOATS * sizeof(float), stream);
    passA<<<NB_EDGE + NB_EMB, 256, 0, stream>>>(sij, ei, s, t, hg, Hm, out, ws);
    passB<<<NB_EDGE, 256, 0, stream>>>(sij, ei, ws);
    pathK<<<C * G, M, 0, stream>>>(pw, ws);
    finalK<<<1, 256, 0, stream>>>(ws, out);
}